// Round 8
// baseline (161.388 us; speedup 1.0000x reference)
//
#include <hip/hip_runtime.h>

// out[b,h] = sum_{i,j} cb[h, i*64+j] * in1[b,i] * in2[b,j]
// B = 4096, dim1 = dim2 = 64, H = 4096.
//
// Round-14: SOFTWARE-PIPELINED OPERAND LOADS. R8-R13 falsified issue
// width, barriers, occupancy, write path, branches, workspace. Remaining
// invariant: aa/bb loads are control-dependent (inside the 16-way switch)
// -> compiler cannot hoist or pipeline them; every quarter exposes
// ~200-300cy of L2 latency, stalling all waves in lockstep (VALUBusy
// pinned ~35%). Fix: padded 7-element load sets are ALWAYS in-bounds
// (i1,i2 <= 57), so operands are loaded unconditionally into 3 rotating
// named register stages, issued 2 rows ahead of consumption (fully
// unrolled 8-row pipeline, static stage naming). The sparse switch still
// executes only the needed FMAs. Also: prep vectorized (float4 table
// writes). Workspace fills are unconditional (R13), so ws use is free.

typedef float vf2 __attribute__((ext_vector_type(2)));

#define SOHF 66   // so row stride in floats

__constant__ int   kStart[7] = {0, 64, 496, 1376, 2496, 3360, 3888};
__constant__ unsigned kMagic[7] = {262144u, 87382u, 52429u, 37450u, 29128u, 23832u, 20165u}; // 2^18/d rounded up, d=2*l3+1
__constant__ int   kVpOff[7] = {0, 4, 13, 24, 34, 40, 43};
__constant__ unsigned char kVp[44] = {
  0, 5, 10, 15,                                  // l3=0
  1, 4, 5, 6, 9, 10, 11, 14, 15,                 // l3=1
  2, 5, 6, 7, 8, 9, 10, 11, 13, 14, 15,          // l3=2 ((1,3) before (2,0))
  3, 6, 7, 9, 10, 11, 12, 13, 14, 15,            // l3=3 ((2,3) before (3,0))
  7, 10, 11, 13, 14, 15,                         // l3=4
  11, 14, 15,                                    // l3=5
  15};                                           // l3=6
__constant__ int kBase[4] = {0, 4, 16, 36};  // offset of first slot of each l

__device__ __forceinline__ void decode_h(int h, int& i1, int& i2,
                                         int& n1, int& n2, int& l1l2) {
  int l3 = (h >= 64) + (h >= 496) + (h >= 1376) + (h >= 2496) + (h >= 3360) + (h >= 3888);
  unsigned hl = (unsigned)(h - kStart[l3]);
  int pair = (int)((hl * kMagic[l3]) >> 18);   // hl / (2*l3+1), exact in range
  int slot = pair & 15;
  int vp   = pair >> 4;
  l1l2 = (int)kVp[kVpOff[l3] + vp];
  int l1 = l1l2 >> 2, l2 = l1l2 & 3;
  n1 = 2 * l1 + 1;
  n2 = 2 * l2 + 1;
  i1 = kBase[l1] + (slot >> 2) * n1;
  i2 = kBase[l2] + (slot & 3) * n2;
}

// ---- merged prep (blocks 0..255, vectorized) + interleave (256..767) ----
__global__ __launch_bounds__(256) void prep_inter_kernel(
    const float* __restrict__ cb, const float* __restrict__ in1,
    const float* __restrict__ in2, float* __restrict__ table,
    int* __restrict__ meta, vf2* __restrict__ t1, vf2* __restrict__ t2) {
  int bid = blockIdx.x;
  if (bid < 256) {
    int idx = bid * 256 + threadIdx.x;   // 65536 = 4096 h x 16 thr
    int h = idx >> 4, e4 = (idx & 15) << 2;
    int i1, i2, n1, n2, c;
    decode_h(h, i1, i2, n1, n2, c);
    if (e4 == 0) meta[h] = i1 | (i2 << 8) | (c << 16);
    unsigned mg = (n2 == 1) ? 65536u : (n2 == 3) ? 21846u : (n2 == 5) ? 13108u : 9363u;
    float4 v;
    float* vp = reinterpret_cast<float*>(&v);
#pragma unroll
    for (int k = 0; k < 4; ++k) {
      int e = e4 + k;
      int qi = (int)(((unsigned)e * mg) >> 16);   // e / n2, exact for e < 64
      int rj = e - qi * n2;
      float x = 0.f;
      if (e < n1 * n2) x = cb[(size_t)h * 4096 + (i1 + qi) * 64 + (i2 + rj)];
      vp[k] = x;
    }
    *reinterpret_cast<float4*>(&table[(size_t)h * 64 + e4]) = v;
  } else {
    int idx = (bid - 256) * 256 + threadIdx.x;   // 131072
    int d = idx & 63;            // FAST -> coalesced 256B row reads
    int t = (idx >> 6) & 63;
    int bt = idx >> 12;
    size_t src = (size_t)(bt * 128 + 2 * t) * 64 + d;
    size_t dst = (size_t)((bt * 64 + d) * 64 + t);
    vf2 u; u.x = in1[src]; u.y = in1[src + 64];
    t1[dst] = u;
    vf2 v2; v2.x = in2[src]; v2.y = in2[src + 64];
    t2[dst] = v2;
  }
}

__device__ __forceinline__ float lane_bcast(float v, int l) {
  union { float f; int i; } u;
  u.f = v;
  u.i = __builtin_amdgcn_readlane(u.i, l);
  return u.f;
}

__device__ __forceinline__ vf2 splat(float c) { vf2 r; r.x = c; r.y = c; return r; }

// sparse compute on pre-loaded padded register stage (consumes subset)
template <int N1, int N2>
__device__ __forceinline__ vf2 inner_tp(float vrow,
                                        const vf2 (&aa)[7],
                                        const vf2 (&bb)[7]) {
  vf2 acc0 = splat(0.f), acc1 = splat(0.f);
#pragma unroll
  for (int i = 0; i < N1; ++i) {
    vf2 t = splat(lane_bcast(vrow, i * N2)) * bb[0];
#pragma unroll
    for (int j = 1; j < N2; ++j)
      t = __builtin_elementwise_fma(splat(lane_bcast(vrow, i * N2 + j)), bb[j], t);
    if (i & 1) acc1 = __builtin_elementwise_fma(aa[i], t, acc1);
    else       acc0 = __builtin_elementwise_fma(aa[i], t, acc0);
  }
  return acc0 + acc1;
}

__global__ __launch_bounds__(512, 4) void tp_kernel(
    const vf2* __restrict__ g1t, const vf2* __restrict__ g2t,
    const float* __restrict__ table, const int* __restrict__ meta,
    float* __restrict__ out) {
  __shared__ float so[128 * SOHF];   // 33792 B full 128b x 64h tile

  const int tid = threadIdx.x;
  const int h0 = blockIdx.x << 6;   // h tile (64) -- FAST grid dim
  const int b0 = blockIdx.y << 7;   // batch tile (128)
  const int w = tid >> 6;           // wave id 0..7
  const int t = tid & 63;           // lane = batch PAIR (2t, 2t+1)

  // ---- preload ALL 8 rows' cb fragments + meta (rows 16q+2w, +1) ----
  const float* tb = table + ((size_t)(h0 + 2 * w) << 6) + t;
  float cur[8];
#pragma unroll
  for (int q = 0; q < 4; ++q) {
    cur[2 * q]     = tb[q << 10];
    cur[2 * q + 1] = tb[(q << 10) + 64];
  }
  const int2* meta2 = reinterpret_cast<const int2*>(meta);
  int m[8];
#pragma unroll
  for (int q = 0; q < 4; ++q) {
    int2 mq = meta2[__builtin_amdgcn_readfirstlane((h0 >> 1) + 8 * q + w)];
    m[2 * q] = mq.x;
    m[2 * q + 1] = mq.y;
  }

  // lane's column base in the interleaved-transposed input tiles
  const vf2* g1 = g1t + ((size_t)blockIdx.y << 12) + t;
  const vf2* g2 = g2t + ((size_t)blockIdx.y << 12) + t;

  // ---- 3 rotating register stages, depth-2 prefetch, fully unrolled ----
  vf2 A0[7], B0[7], A1[7], B1[7], A2[7], B2[7];

#define LOADR(MM, A, B) do {                          \
    int li1 = (MM) & 255, li2 = ((MM) >> 8) & 255;    \
    const vf2* ap_ = g1 + (li1 << 6);                 \
    const vf2* bp_ = g2 + (li2 << 6);                 \
    _Pragma("unroll")                                 \
    for (int i_ = 0; i_ < 7; ++i_) A[i_] = ap_[i_ << 6]; \
    _Pragma("unroll")                                 \
    for (int j_ = 0; j_ < 7; ++j_) B[j_] = bp_[j_ << 6]; \
  } while (0)

#define SWITCH16(VR, A, B, RR, MM)                    \
  switch ((MM) >> 16) {                               \
    case 0:  RR = inner_tp<1, 1>(VR, A, B); break;    \
    case 1:  RR = inner_tp<1, 3>(VR, A, B); break;    \
    case 2:  RR = inner_tp<1, 5>(VR, A, B); break;    \
    case 3:  RR = inner_tp<1, 7>(VR, A, B); break;    \
    case 4:  RR = inner_tp<3, 1>(VR, A, B); break;    \
    case 5:  RR = inner_tp<3, 3>(VR, A, B); break;    \
    case 6:  RR = inner_tp<3, 5>(VR, A, B); break;    \
    case 7:  RR = inner_tp<3, 7>(VR, A, B); break;    \
    case 8:  RR = inner_tp<5, 1>(VR, A, B); break;    \
    case 9:  RR = inner_tp<5, 3>(VR, A, B); break;    \
    case 10: RR = inner_tp<5, 5>(VR, A, B); break;    \
    case 11: RR = inner_tp<5, 7>(VR, A, B); break;    \
    case 12: RR = inner_tp<7, 1>(VR, A, B); break;    \
    case 13: RR = inner_tp<7, 3>(VR, A, B); break;    \
    case 14: RR = inner_tp<7, 5>(VR, A, B); break;    \
    default: RR = inner_tp<7, 7>(VR, A, B); break;    \
  }

#define STORE_PAIR(Q, RE, RO) do {                                        \
    vf2 va; va.x = (RE).x; va.y = (RO).x;                                 \
    vf2 vb; vb.x = (RE).y; vb.y = (RO).y;                                 \
    *reinterpret_cast<vf2*>(&so[(2 * t) * SOHF + 16 * (Q) + 2 * w]) = va; \
    *reinterpret_cast<vf2*>(&so[(2 * t + 1) * SOHF + 16 * (Q) + 2 * w]) = vb; \
  } while (0)

  vf2 rp, rr;
  LOADR(m[0], A0, B0);                                   // prologue
  LOADR(m[1], A1, B1);

  LOADR(m[2], A2, B2); SWITCH16(cur[0], A0, B0, rp, m[0]);
  LOADR(m[3], A0, B0); SWITCH16(cur[1], A1, B1, rr, m[1]); STORE_PAIR(0, rp, rr);
  LOADR(m[4], A1, B1); SWITCH16(cur[2], A2, B2, rp, m[2]);
  LOADR(m[5], A2, B2); SWITCH16(cur[3], A0, B0, rr, m[3]); STORE_PAIR(1, rp, rr);
  LOADR(m[6], A0, B0); SWITCH16(cur[4], A1, B1, rp, m[4]);
  LOADR(m[7], A1, B1); SWITCH16(cur[5], A2, B2, rr, m[5]); STORE_PAIR(2, rp, rr);
  SWITCH16(cur[6], A0, B0, rp, m[6]);
  SWITCH16(cur[7], A1, B1, rr, m[7]); STORE_PAIR(3, rp, rr);

#undef LOADR
#undef SWITCH16
#undef STORE_PAIR

  __syncthreads();   // single barrier: tile complete

  // ---- flush: 4 insts x float4; lanes 0..15 cover 256B contiguous per row ----
#pragma unroll
  for (int k = 0; k < 4; ++k) {
    int row = 32 * k + (tid >> 4);    // 0..127
    int c4  = tid & 15;               // float4 index 0..15
    const float* sp = &so[row * SOHF + 4 * c4];
    vf2 u0 = *reinterpret_cast<const vf2*>(sp);
    vf2 u1 = *reinterpret_cast<const vf2*>(sp + 2);
    float4 v; v.x = u0.x; v.y = u0.y; v.z = u1.x; v.w = u1.y;
    *reinterpret_cast<float4*>(out + (size_t)(b0 + row) * 4096 + h0 + 4 * c4) = v;
  }
}

extern "C" void kernel_launch(void* const* d_in, const int* in_sizes, int n_in,
                              void* d_out, int out_size, void* d_ws, size_t ws_size,
                              hipStream_t stream) {
  const float* in1 = (const float*)d_in[0];
  const float* in2 = (const float*)d_in[1];
  const float* cb  = (const float*)d_in[2];
  float* out = (float*)d_out;
  char* ws = (char*)d_ws;
  float* table = (float*)ws;                               // 1 MB @ 0
  int*   meta  = (int*)(ws + ((size_t)1 << 20));           // 16 KB @ 1 MB
  vf2*   inT1  = (vf2*)(ws + ((size_t)2 << 20));           // 1 MB @ 2 MB
  vf2*   inT2  = (vf2*)(ws + ((size_t)3 << 20));           // 1 MB @ 3 MB
  (void)in_sizes; (void)n_in; (void)out_size; (void)ws_size;
  prep_inter_kernel<<<768, 256, 0, stream>>>(cb, in1, in2, table, meta, inT1, inT2);
  tp_kernel<<<dim3(64, 32), 512, 0, stream>>>(inT1, inT2, table, meta, out);
}

// Round 9
// 142.070 us; speedup vs baseline: 1.1360x; 1.1360x over previous
//
#include <hip/hip_runtime.h>

// out[b,h] = sum_{i,j} cb[h, i*64+j] * in1[b,i] * in2[b,j]
// B = 4096, dim1 = dim2 = 64, H = 4096.
//
// Round-15: 4-BATCH LANES (vf4). Calibrated model from R12/R14: duration
// tracks total wave-instruction count at ~35% issue efficiency; no pipe
// saturates. So cut instructions per batch: lane carries 4 batches. Per
// row, n1*n2 readlanes feed 2*n1*n2 pk-FMAs (was 1:1) and n1+n2 dwordx4
// loads serve 4 batches (was 2 via dwordx2, same inst count - the two
// adjacent vf2 pairs in the unchanged inT layout form one aligned vf4).
// ~1.7x fewer insts per batch. Skeleton = proven R11: switch-internal
// sparse loads (R14 showed hoisting backfires), per-quarter so writes,
// single barrier, contiguous flush. fp32 order unchanged -> same absmax.

typedef float vf2 __attribute__((ext_vector_type(2)));
typedef float vf4 __attribute__((ext_vector_type(4)));

#define SOH2 65   // so row stride in floats (odd -> spreads banks)

__constant__ int   kStart[7] = {0, 64, 496, 1376, 2496, 3360, 3888};
__constant__ unsigned kMagic[7] = {262144u, 87382u, 52429u, 37450u, 29128u, 23832u, 20165u}; // 2^18/d rounded up, d=2*l3+1
__constant__ int   kVpOff[7] = {0, 4, 13, 24, 34, 40, 43};
__constant__ unsigned char kVp[44] = {
  0, 5, 10, 15,                                  // l3=0
  1, 4, 5, 6, 9, 10, 11, 14, 15,                 // l3=1
  2, 5, 6, 7, 8, 9, 10, 11, 13, 14, 15,          // l3=2 ((1,3) before (2,0))
  3, 6, 7, 9, 10, 11, 12, 13, 14, 15,            // l3=3 ((2,3) before (3,0))
  7, 10, 11, 13, 14, 15,                         // l3=4
  11, 14, 15,                                    // l3=5
  15};                                           // l3=6
__constant__ int kBase[4] = {0, 4, 16, 36};  // offset of first slot of each l

__device__ __forceinline__ void decode_h(int h, int& i1, int& i2,
                                         int& n1, int& n2, int& l1l2) {
  int l3 = (h >= 64) + (h >= 496) + (h >= 1376) + (h >= 2496) + (h >= 3360) + (h >= 3888);
  unsigned hl = (unsigned)(h - kStart[l3]);
  int pair = (int)((hl * kMagic[l3]) >> 18);   // hl / (2*l3+1), exact in range
  int slot = pair & 15;
  int vp   = pair >> 4;
  l1l2 = (int)kVp[kVpOff[l3] + vp];
  int l1 = l1l2 >> 2, l2 = l1l2 & 3;
  n1 = 2 * l1 + 1;
  n2 = 2 * l2 + 1;
  i1 = kBase[l1] + (slot >> 2) * n1;
  i2 = kBase[l2] + (slot & 3) * n2;
}

// ---- merged prep (blocks 0..255, vectorized) + interleave (256..767) ----
__global__ __launch_bounds__(256) void prep_inter_kernel(
    const float* __restrict__ cb, const float* __restrict__ in1,
    const float* __restrict__ in2, float* __restrict__ table,
    int* __restrict__ meta, vf2* __restrict__ t1, vf2* __restrict__ t2) {
  int bid = blockIdx.x;
  if (bid < 256) {
    int idx = bid * 256 + threadIdx.x;   // 65536 = 4096 h x 16 thr
    int h = idx >> 4, e4 = (idx & 15) << 2;
    int i1, i2, n1, n2, c;
    decode_h(h, i1, i2, n1, n2, c);
    if (e4 == 0) meta[h] = i1 | (i2 << 8) | (c << 16);
    unsigned mg = (n2 == 1) ? 65536u : (n2 == 3) ? 21846u : (n2 == 5) ? 13108u : 9363u;
    float4 v;
    float* vp = reinterpret_cast<float*>(&v);
#pragma unroll
    for (int k = 0; k < 4; ++k) {
      int e = e4 + k;
      int qi = (int)(((unsigned)e * mg) >> 16);   // e / n2, exact for e < 64
      int rj = e - qi * n2;
      float x = 0.f;
      if (e < n1 * n2) x = cb[(size_t)h * 4096 + (i1 + qi) * 64 + (i2 + rj)];
      vp[k] = x;
    }
    *reinterpret_cast<float4*>(&table[(size_t)h * 64 + e4]) = v;
  } else {
    int idx = (bid - 256) * 256 + threadIdx.x;   // 131072
    int d = idx & 63;            // FAST -> coalesced 256B row reads
    int t = (idx >> 6) & 63;
    int bt = idx >> 12;
    size_t src = (size_t)(bt * 128 + 2 * t) * 64 + d;
    size_t dst = (size_t)((bt * 64 + d) * 64 + t);
    vf2 u; u.x = in1[src]; u.y = in1[src + 64];
    t1[dst] = u;
    vf2 v2; v2.x = in2[src]; v2.y = in2[src + 64];
    t2[dst] = v2;
  }
}

__device__ __forceinline__ float lane_bcast(float v, int l) {
  union { float f; int i; } u;
  u.f = v;
  u.i = __builtin_amdgcn_readlane(u.i, l);
  return u.f;
}

__device__ __forceinline__ vf4 splat4(float c) {
  vf4 r; r.x = c; r.y = c; r.z = c; r.w = c; return r;
}

// single row, 4 batches packed; g1/g2 = lane's vf4 column base (vf2 units)
template <int N1, int N2>
__device__ __forceinline__ vf4 inner_tp(float vrow,
                                        const vf2* __restrict__ g1,
                                        const vf2* __restrict__ g2,
                                        int i1, int i2) {
  vf4 bb[N2], aa[N1];
#pragma unroll
  for (int j = 0; j < N2; ++j)
    bb[j] = *reinterpret_cast<const vf4*>(g2 + ((i2 + j) << 6));
#pragma unroll
  for (int i = 0; i < N1; ++i)
    aa[i] = *reinterpret_cast<const vf4*>(g1 + ((i1 + i) << 6));
  vf4 acc0 = splat4(0.f), acc1 = splat4(0.f);
#pragma unroll
  for (int i = 0; i < N1; ++i) {
    vf4 t = splat4(lane_bcast(vrow, i * N2)) * bb[0];
#pragma unroll
    for (int j = 1; j < N2; ++j)
      t = __builtin_elementwise_fma(splat4(lane_bcast(vrow, i * N2 + j)), bb[j], t);
    if (i & 1) acc1 = __builtin_elementwise_fma(aa[i], t, acc1);
    else       acc0 = __builtin_elementwise_fma(aa[i], t, acc0);
  }
  return acc0 + acc1;
}

// fused same-run pair x 4 batches: aa/bb loaded once for both rows
template <int N1, int N2>
__device__ __forceinline__ void inner_tp2(float v0, float v1,
                                          const vf2* __restrict__ g1,
                                          const vf2* __restrict__ g2,
                                          int i1, int i2,
                                          vf4& o0, vf4& o1) {
  vf4 bb[N2], aa[N1];
#pragma unroll
  for (int j = 0; j < N2; ++j)
    bb[j] = *reinterpret_cast<const vf4*>(g2 + ((i2 + j) << 6));
#pragma unroll
  for (int i = 0; i < N1; ++i)
    aa[i] = *reinterpret_cast<const vf4*>(g1 + ((i1 + i) << 6));
  vf4 a0 = splat4(0.f), a1 = splat4(0.f), b0 = splat4(0.f), b1 = splat4(0.f);
#pragma unroll
  for (int i = 0; i < N1; ++i) {
    vf4 t0 = splat4(lane_bcast(v0, i * N2)) * bb[0];
    vf4 t1 = splat4(lane_bcast(v1, i * N2)) * bb[0];
#pragma unroll
    for (int j = 1; j < N2; ++j) {
      t0 = __builtin_elementwise_fma(splat4(lane_bcast(v0, i * N2 + j)), bb[j], t0);
      t1 = __builtin_elementwise_fma(splat4(lane_bcast(v1, i * N2 + j)), bb[j], t1);
    }
    if (i & 1) { a1 = __builtin_elementwise_fma(aa[i], t0, a1);
                 b1 = __builtin_elementwise_fma(aa[i], t1, b1); }
    else       { a0 = __builtin_elementwise_fma(aa[i], t0, a0);
                 b0 = __builtin_elementwise_fma(aa[i], t1, b0); }
  }
  o0 = a0 + a1;
  o1 = b0 + b1;
}

__global__ __launch_bounds__(512, 4) void tp_kernel(
    const vf2* __restrict__ g1t, const vf2* __restrict__ g2t,
    const float* __restrict__ table, const int* __restrict__ meta,
    float* __restrict__ out) {
  __shared__ float so[256 * SOH2];   // 66560 B full 256b x 64h tile

  const int tid = threadIdx.x;
  const int h0 = blockIdx.x << 6;   // h tile (64) -- FAST grid dim
  const int b0 = blockIdx.y << 8;   // batch tile (256)
  const int w = tid >> 6;           // wave id 0..7: rows 16q+2w, +1
  const int t = tid & 63;           // lane = batch QUAD (4t .. 4t+3)

  // wave's cb-table rows; lane t holds entry t. Prefetch quarter 0 now.
  const float* tb = table + ((size_t)(h0 + 2 * w) << 6) + t;
  float cur0 = tb[0];
  float cur1 = tb[64];
  const int2* meta2 = reinterpret_cast<const int2*>(meta);
  int2 mcur = meta2[__builtin_amdgcn_readfirstlane((h0 >> 1) + w)];

  // lane's vf4 base in inT (vf2 units): pairs 2t, 2t+1 are adjacent.
  // bty covers 2 legacy 128-batch tiles (8192 vf2 each... 4096 vf2/tile).
  const int tt = 2 * t;
  const size_t lane_off = ((size_t)blockIdx.y << 13) + ((tt >> 6) << 12) + (tt & 63);
  const vf2* g1 = g1t + lane_off;
  const vf2* g2 = g2t + lane_off;

#pragma unroll 1
  for (int q = 0; q < 4; ++q) {
    // prefetch next quarter's cb pair + meta (clamped on last iteration)
    int qn = (q < 3) ? (q + 1) : 0;
    float nxt0 = tb[qn << 10];
    float nxt1 = tb[(qn << 10) + 64];
    int2 mnxt = meta2[__builtin_amdgcn_readfirstlane((h0 >> 1) + 8 * qn + w)];

    int mm0 = mcur.x, mm1 = mcur.y;
    vf4 r0 = splat4(0.f), r1 = splat4(0.f);
    if (mm0 == mm1) {
      int i1 = mm0 & 255, i2 = (mm0 >> 8) & 255;
#define TP2_CASE(L1, L2) \
      case (L1 * 4 + L2): inner_tp2<2 * L1 + 1, 2 * L2 + 1>(cur0, cur1, g1, g2, i1, i2, r0, r1); break;
      switch (mm0 >> 16) {
        TP2_CASE(0, 0) TP2_CASE(0, 1) TP2_CASE(0, 2) TP2_CASE(0, 3)
        TP2_CASE(1, 0) TP2_CASE(1, 1) TP2_CASE(1, 2) TP2_CASE(1, 3)
        TP2_CASE(2, 0) TP2_CASE(2, 1) TP2_CASE(2, 2) TP2_CASE(2, 3)
        TP2_CASE(3, 0) TP2_CASE(3, 1) TP2_CASE(3, 2) TP2_CASE(3, 3)
        default: break;
      }
#undef TP2_CASE
    } else {
#define TP_CASE(L1, L2, VR, DST, MI1, MI2) \
      case (L1 * 4 + L2): DST = inner_tp<2 * L1 + 1, 2 * L2 + 1>(VR, g1, g2, MI1, MI2); break;
      {
        int i1 = mm0 & 255, i2 = (mm0 >> 8) & 255;
        switch (mm0 >> 16) {
          TP_CASE(0, 0, cur0, r0, i1, i2) TP_CASE(0, 1, cur0, r0, i1, i2)
          TP_CASE(0, 2, cur0, r0, i1, i2) TP_CASE(0, 3, cur0, r0, i1, i2)
          TP_CASE(1, 0, cur0, r0, i1, i2) TP_CASE(1, 1, cur0, r0, i1, i2)
          TP_CASE(1, 2, cur0, r0, i1, i2) TP_CASE(1, 3, cur0, r0, i1, i2)
          TP_CASE(2, 0, cur0, r0, i1, i2) TP_CASE(2, 1, cur0, r0, i1, i2)
          TP_CASE(2, 2, cur0, r0, i1, i2) TP_CASE(2, 3, cur0, r0, i1, i2)
          TP_CASE(3, 0, cur0, r0, i1, i2) TP_CASE(3, 1, cur0, r0, i1, i2)
          TP_CASE(3, 2, cur0, r0, i1, i2) TP_CASE(3, 3, cur0, r0, i1, i2)
          default: break;
        }
      }
      {
        int i1 = mm1 & 255, i2 = (mm1 >> 8) & 255;
        switch (mm1 >> 16) {
          TP_CASE(0, 0, cur1, r1, i1, i2) TP_CASE(0, 1, cur1, r1, i1, i2)
          TP_CASE(0, 2, cur1, r1, i1, i2) TP_CASE(0, 3, cur1, r1, i1, i2)
          TP_CASE(1, 0, cur1, r1, i1, i2) TP_CASE(1, 1, cur1, r1, i1, i2)
          TP_CASE(1, 2, cur1, r1, i1, i2) TP_CASE(1, 3, cur1, r1, i1, i2)
          TP_CASE(2, 0, cur1, r1, i1, i2) TP_CASE(2, 1, cur1, r1, i1, i2)
          TP_CASE(2, 2, cur1, r1, i1, i2) TP_CASE(2, 3, cur1, r1, i1, i2)
          TP_CASE(3, 0, cur1, r1, i1, i2) TP_CASE(3, 1, cur1, r1, i1, i2)
          TP_CASE(3, 2, cur1, r1, i1, i2) TP_CASE(3, 3, cur1, r1, i1, i2)
          default: break;
        }
      }
#undef TP_CASE
    }
    // so[batch][h]: lane's 4 batch rows, cols 16q+2w (row h_a), +1 (row h_b)
    {
      const float r0a[4] = {r0.x, r0.y, r0.z, r0.w};
      const float r1a[4] = {r1.x, r1.y, r1.z, r1.w};
#pragma unroll
      for (int k = 0; k < 4; ++k) {
        vf2 u; u.x = r0a[k]; u.y = r1a[k];
        *reinterpret_cast<vf2*>(&so[(4 * t + k) * SOH2 + 16 * q + 2 * w]) = u;
      }
    }
    cur0 = nxt0; cur1 = nxt1;
    mcur = mnxt;
  }

  __syncthreads();   // single barrier: tile complete

  // ---- flush: 2 threads/row, each 32 contiguous floats (8 x float4) ----
  {
    int row = tid >> 1;               // 0..255
    int hs = (tid & 1) << 5;          // 0 or 32
    const float* sp = &so[row * SOH2 + hs];
    float* op = out + (size_t)(b0 + row) * 4096 + h0 + hs;
#pragma unroll
    for (int m = 0; m < 8; ++m) {
      float4 v;
      v.x = sp[4 * m]; v.y = sp[4 * m + 1]; v.z = sp[4 * m + 2]; v.w = sp[4 * m + 3];
      *reinterpret_cast<float4*>(op + 4 * m) = v;
    }
  }
}

extern "C" void kernel_launch(void* const* d_in, const int* in_sizes, int n_in,
                              void* d_out, int out_size, void* d_ws, size_t ws_size,
                              hipStream_t stream) {
  const float* in1 = (const float*)d_in[0];
  const float* in2 = (const float*)d_in[1];
  const float* cb  = (const float*)d_in[2];
  float* out = (float*)d_out;
  char* ws = (char*)d_ws;
  float* table = (float*)ws;                               // 1 MB @ 0
  int*   meta  = (int*)(ws + ((size_t)1 << 20));           // 16 KB @ 1 MB
  vf2*   inT1  = (vf2*)(ws + ((size_t)2 << 20));           // 1 MB @ 2 MB
  vf2*   inT2  = (vf2*)(ws + ((size_t)3 << 20));           // 1 MB @ 3 MB
  (void)in_sizes; (void)n_in; (void)out_size; (void)ws_size;
  prep_inter_kernel<<<768, 256, 0, stream>>>(cb, in1, in2, table, meta, inT1, inT2);
  tp_kernel<<<dim3(64, 16), 512, 0, stream>>>(inT1, inT2, table, meta, out);
}